// Round 9
// baseline (2227.180 us; speedup 1.0000x reference)
//
#include <hip/hip_runtime.h>
#include <hip/hip_bf16.h>

// Problem constants (from reference)
#define NN 100000      // nodes
#define FF 128         // F_IN
#define HH 64          // HID
#define BN_EPS 1e-5f

typedef unsigned int uint_t;

// ---------------- bf16 helpers (RNE) ----------------
__device__ __forceinline__ float bflo(uint_t u) { return __uint_as_float(u << 16); }
__device__ __forceinline__ float bfhi(uint_t u) { return __uint_as_float(u & 0xFFFF0000u); }
__device__ __forceinline__ unsigned short f2bf(float f) {
    uint_t a = __float_as_uint(f); a += 0x7FFF + ((a >> 16) & 1); return (unsigned short)(a >> 16);
}
__device__ __forceinline__ uint_t f2bf2(float lo, float hi) {
    uint_t a = __float_as_uint(lo); a += 0x7FFF + ((a >> 16) & 1);
    uint_t b = __float_as_uint(hi); b += 0x7FFF + ((b >> 16) & 1);
    return (a >> 16) | (b & 0xFFFF0000u);
}

// ---------------- dtype detection (int64 vs int32 edge/batch) ----------------
__global__ void k_detect(const unsigned* __restrict__ ei, int* __restrict__ flag) {
    if (threadIdx.x == 0 && blockIdx.x == 0) {
        unsigned o = 0;
        for (int i = 1; i < 32; i += 2) o |= ei[i];   // high words if int64
        *flag = (o == 0) ? 1 : 0;                      // 1 => int64
    }
}

__device__ __forceinline__ int load_idx(const void* p, int i, int is64) {
    return is64 ? (int)((const long long*)p)[i] : ((const int*)p)[i];
}

// ---------------- degree count ----------------
__global__ void k_count(const void* __restrict__ ei, int E, const int* __restrict__ flag,
                        int* __restrict__ counts) {
    int e = blockIdx.x * blockDim.x + threadIdx.x;
    if (e >= E) return;
    int is64 = *flag;
    int d = load_idx(ei, E + e, is64);   // dst row is second half
    atomicAdd(&counts[d], 1);
}

// ---------------- dinv + per-graph node counts ----------------
__global__ void k_dinv(const int* __restrict__ counts, float* __restrict__ dinv,
                       const void* __restrict__ bat, const int* __restrict__ flag,
                       int* __restrict__ gcnt, int N) {
    int i = blockIdx.x * blockDim.x + threadIdx.x;
    if (i >= N) return;
    float deg = (float)counts[i] + 1.0f;
    dinv[i] = rsqrtf(deg);
    int is64 = *flag;
    int b = load_idx(bat, i, is64);
    atomicAdd(&gcnt[b], 1);
}

// ---------------- 3-kernel exclusive scan (chunk = 512) ----------------
__global__ void k_scan1(const int* __restrict__ counts, int* __restrict__ partial, int N) {
    __shared__ int s[512];
    int t = threadIdx.x;
    int i = blockIdx.x * 512 + t;
    int v = (i < N) ? counts[i] : 0;
    s[t] = v; __syncthreads();
    for (int off = 256; off; off >>= 1) {
        if (t < off) s[t] += s[t + off];
        __syncthreads();
    }
    if (t == 0) partial[blockIdx.x] = s[0];
}

__global__ void k_scan2(int* __restrict__ partial, int nch) {
    __shared__ int s[256];
    int t = threadIdx.x;
    int v = (t < nch) ? partial[t] : 0;
    s[t] = v; __syncthreads();
    for (int off = 1; off < 256; off <<= 1) {
        int add = (t >= off) ? s[t - off] : 0;
        __syncthreads();
        s[t] += add;
        __syncthreads();
    }
    if (t < nch) partial[t] = s[t] - v;   // exclusive
}

__global__ void k_scan3(const int* __restrict__ counts, const int* __restrict__ partial,
                        int* __restrict__ rp, int N, int E) {
    __shared__ int s[512];
    int t = threadIdx.x;
    int i = blockIdx.x * 512 + t;
    int v = (i < N) ? counts[i] : 0;
    s[t] = v; __syncthreads();
    for (int off = 1; off < 512; off <<= 1) {
        int add = (t >= off) ? s[t - off] : 0;
        __syncthreads();
        s[t] += add;
        __syncthreads();
    }
    if (i < N) rp[i] = partial[blockIdx.x] + s[t] - v;
    if (i == N) rp[N] = E;
}

// ---------------- CSR fill: packed {src, w} ----------------
__global__ void k_fill(const void* __restrict__ ei, int E, const int* __restrict__ flag,
                       const float* __restrict__ dinv, const int* __restrict__ rp,
                       int* __restrict__ fillcnt, int2* __restrict__ cw) {
    int e = blockIdx.x * blockDim.x + threadIdx.x;
    if (e >= E) return;
    int is64 = *flag;
    int s = load_idx(ei, e, is64);
    int d = load_idx(ei, E + e, is64);
    float w = dinv[s] * dinv[d];
    int pos = rp[d] + atomicAdd(&fillcnt[d], 1);
    int2 p; p.x = s; p.y = __float_as_int(w);
    cw[pos] = p;
}

// ---------------- BN constant folding ----------------
__global__ void k_prep(const float* b1, const float* g1, const float* be1,
                       const float* m1, const float* v1,
                       const float* b2, const float* g2, const float* be2,
                       const float* m2, const float* v2,
                       float* sc1, float* sh1, float* sc2, float* sh2) {
    int f = threadIdx.x;
    if (f < HH) {
        float s1 = g1[f] * rsqrtf(v1[f] + BN_EPS);
        sc1[f] = s1; sh1[f] = (b1[f] - m1[f]) * s1 + be1[f];
        float s2 = g2[f] * rsqrtf(v2[f] + BN_EPS);
        sc2[f] = s2; sh2[f] = (b2[f] - m2[f]) * s2 + be2[f];
    }
}

// ---------------- dense GEMM -> quartered bf16 planes ----------------
// out plane layout: hq[p][n][16], p = f>>4 (3.2 MB per plane -> L2-resident)
__device__ __forceinline__ float ldf(const float* p, int i) { return p[i]; }
__device__ __forceinline__ float ldf(const unsigned short* p, int i) {
    return __uint_as_float((uint_t)p[i] << 16);
}

template <int K, int NPB, typename Tin>
__global__ void k_gemm(const Tin* __restrict__ x, const float* __restrict__ W,
                       unsigned short* __restrict__ outq, int N) {
    __shared__ float wT[K * (HH + 1)];
    __shared__ float xs[NPB * K];
    const int TB = NPB * 64;
    int t = threadIdx.x;
    for (int idx = t; idx < K * HH; idx += TB) {
        int f = idx / K, k = idx % K;
        wT[k * (HH + 1) + f] = W[idx];
    }
    int nb = blockIdx.x * NPB;
    for (int idx = t; idx < NPB * K; idx += TB) {
        int gi = nb * K + idx;
        xs[idx] = (gi < N * K) ? ldf(x, gi) : 0.0f;
    }
    __syncthreads();
    int f = t & 63, nl = t >> 6;
    float acc = 0.0f;
#pragma unroll
    for (int k = 0; k < K; k++)
        acc += xs[nl * K + k] * wT[k * (HH + 1) + f];
    int n = nb + nl;
    if (n < N) outq[(f >> 4) * (N * 16) + n * 16 + (f & 15)] = f2bf(acc);
}

// ---------------- quartered aggregation: pass = blockIdx.y over 4 planes ------
// Per pass the gather target is one 3.2 MB plane -> L2-resident on every XCD.
// Lane layout: es = lane>>2 (16 edge slots), c = lane&3 (uint2 = 4 bf16 feats).
// One load instruction gathers 16 rows x 32 B; unroll 2 -> 32 edges in flight.
template <int LAYER>
__global__ void k_agg(const unsigned short* __restrict__ hq, const int2* __restrict__ cw,
                      const int* __restrict__ rp, const float* __restrict__ dinv,
                      const float* __restrict__ sc, const float* __restrict__ sh,
                      unsigned short* __restrict__ out,
                      const void* __restrict__ bat, const int* __restrict__ flag,
                      const float* __restrict__ Wl, float* __restrict__ gsum, int N) {
    int pass = blockIdx.y;
    int wid = (int)((blockIdx.x * blockDim.x + threadIdx.x) >> 6);
    if (wid >= N) return;
    int lane = threadIdx.x & 63;
    int es = lane >> 2;      // edge slot 0..15
    int c  = lane & 3;       // uint2 chunk (4 bf16 features)
    const uint2* __restrict__ hp = (const uint2*)hq + (size_t)pass * N * 4;

    int s = rp[wid], e = rp[wid + 1];
    float a0 = 0.f, a1 = 0.f, a2 = 0.f, a3 = 0.f;
    if (e > s) {
        int last = e - 1;
        for (int j0 = s; j0 < e; j0 += 32) {
            int j1 = j0 + es, j2 = j0 + 16 + es;
            int2 p0 = cw[j1 < last ? j1 : last];
            int2 p1 = cw[j2 < last ? j2 : last];
            float w0 = (j1 < e) ? __int_as_float(p0.y) : 0.f;
            float w1 = (j2 < e) ? __int_as_float(p1.y) : 0.f;
            uint2 r0 = hp[p0.x * 4 + c];
            uint2 r1 = hp[p1.x * 4 + c];
            a0 += w0 * bflo(r0.x) + w1 * bflo(r1.x);
            a1 += w0 * bfhi(r0.x) + w1 * bfhi(r1.x);
            a2 += w0 * bflo(r0.y) + w1 * bflo(r1.y);
            a3 += w0 * bfhi(r0.y) + w1 * bfhi(r1.y);
        }
    }
    // reduce across the 16 edge slots (lane bits 2..5)
#pragma unroll
    for (int off = 4; off <= 32; off <<= 1) {
        a0 += __shfl_xor(a0, off); a1 += __shfl_xor(a1, off);
        a2 += __shfl_xor(a2, off); a3 += __shfl_xor(a3, off);
    }
    if (lane < 4) {
        // self-loop term
        float di = dinv[wid], di2 = di * di;
        uint2 sr = hp[wid * 4 + c];
        a0 += di2 * bflo(sr.x); a1 += di2 * bfhi(sr.x);
        a2 += di2 * bflo(sr.y); a3 += di2 * bfhi(sr.y);
        int f0 = pass * 16 + c * 4;
        float v0 = fmaxf(a0 * sc[f0 + 0] + sh[f0 + 0], 0.f);
        float v1 = fmaxf(a1 * sc[f0 + 1] + sh[f0 + 1], 0.f);
        float v2 = fmaxf(a2 * sc[f0 + 2] + sh[f0 + 2], 0.f);
        float v3 = fmaxf(a3 * sc[f0 + 3] + sh[f0 + 3], 0.f);
        if (LAYER == 1) {
            // standard [n][64] bf16 rows for GEMM-2
            uint2 o; o.x = f2bf2(v0, v1); o.y = f2bf2(v2, v3);
            ((uint2*)out)[wid * 16 + pass * 4 + c] = o;
        } else {
            float tv = v0 * Wl[f0] + v1 * Wl[f0 + 1] + v2 * Wl[f0 + 2] + v3 * Wl[f0 + 3];
            tv += __shfl_xor(tv, 1);
            tv += __shfl_xor(tv, 2);
            if (c == 0) {
                int is64 = *flag;
                int b = load_idx(bat, wid, is64);
                atomicAdd(&gsum[b], tv);
            }
        }
    }
}

// ---------------- final: mean + linear bias ----------------
__global__ void k_final(const float* __restrict__ gsum, const int* __restrict__ gcnt,
                        const float* __restrict__ bl, float* __restrict__ outp, int G) {
    int g = blockIdx.x * blockDim.x + threadIdx.x;
    if (g < G) outp[g] = gsum[g] / fmaxf((float)gcnt[g], 1.0f) + bl[0];
}

extern "C" void kernel_launch(void* const* d_in, const int* in_sizes, int n_in,
                              void* d_out, int out_size, void* d_ws, size_t ws_size,
                              hipStream_t stream) {
    const float* x   = (const float*)d_in[0];
    const void*  ei  = d_in[1];
    const void*  bat = d_in[2];
    const float* W1  = (const float*)d_in[3];
    const float* b1  = (const float*)d_in[4];
    const float* g1  = (const float*)d_in[5];
    const float* be1 = (const float*)d_in[6];
    const float* m1  = (const float*)d_in[7];
    const float* v1  = (const float*)d_in[8];
    const float* W2  = (const float*)d_in[9];
    const float* b2  = (const float*)d_in[10];
    const float* g2  = (const float*)d_in[11];
    const float* be2 = (const float*)d_in[12];
    const float* m2  = (const float*)d_in[13];
    const float* v2  = (const float*)d_in[14];
    const float* Wl  = (const float*)d_in[15];
    const float* bl  = (const float*)d_in[16];
    float* outp = (float*)d_out;

    const int N = NN;
    const int E = in_sizes[1] / 2;
    const int G = out_size;

    // workspace carve-up (256B aligned)
    char* base = (char*)d_ws;
    size_t off = 0;
    auto alloc = [&](size_t bytes) { void* p = base + off; off = (off + bytes + 255) & ~(size_t)255; return p; };
    int*   flag    = (int*)  alloc(16);
    float* dinv    = (float*)alloc((size_t)N * 4);
    int*   counts  = (int*)  alloc((size_t)N * 4);
    int*   rp      = (int*)  alloc(((size_t)N + 1) * 4);
    int*   fillcnt = (int*)  alloc((size_t)N * 4);
    int*   partial = (int*)  alloc(1024);
    float* sc1     = (float*)alloc(HH * 4);
    float* sh1     = (float*)alloc(HH * 4);
    float* sc2     = (float*)alloc(HH * 4);
    float* sh2     = (float*)alloc(HH * 4);
    float* gsum    = (float*)alloc((size_t)G * 4);
    int*   gcnt    = (int*)  alloc((size_t)G * 4);
    int2*  cw      = (int2*) alloc((size_t)E * 8);
    unsigned short* hqA  = (unsigned short*)alloc((size_t)N * HH * 2);  // quartered planes
    unsigned short* hrow = (unsigned short*)alloc((size_t)N * HH * 2);  // standard rows
    unsigned short* hqB  = (unsigned short*)alloc((size_t)N * HH * 2);  // quartered planes
    (void)ws_size;

    // zero accumulators (fresh every call)
    hipMemsetAsync(counts, 0, (size_t)N * 4, stream);
    hipMemsetAsync(fillcnt, 0, (size_t)N * 4, stream);
    hipMemsetAsync(gsum, 0, (size_t)G * 4, stream);
    hipMemsetAsync(gcnt, 0, (size_t)G * 4, stream);

    k_detect<<<1, 64, 0, stream>>>((const unsigned*)ei, flag);

    int eb = (E + 255) / 256;
    k_count<<<eb, 256, 0, stream>>>(ei, E, flag, counts);

    int nb = (N + 255) / 256;
    k_dinv<<<nb, 256, 0, stream>>>(counts, dinv, bat, flag, gcnt, N);

    int nch = (N + 511) / 512;
    k_scan1<<<nch, 512, 0, stream>>>(counts, partial, N);
    k_scan2<<<1, 256, 0, stream>>>(partial, nch);
    k_scan3<<<nch, 512, 0, stream>>>(counts, partial, rp, N, E);

    k_fill<<<eb, 256, 0, stream>>>(ei, E, flag, dinv, rp, fillcnt, cw);

    k_prep<<<1, 64, 0, stream>>>(b1, g1, be1, m1, v1, b2, g2, be2, m2, v2,
                                 sc1, sh1, sc2, sh2);

    dim3 agrid((N + 3) / 4, 4);   // x = node blocks, y = feature quarter (pass)

    // layer 1: GEMM (f32 in -> quartered bf16), agg (L2-resident plane gather)
    k_gemm<FF, 8, float><<<(N + 7) / 8, 512, 0, stream>>>(x, W1, hqA, N);
    k_agg<1><<<agrid, 256, 0, stream>>>(hqA, cw, rp, dinv, sc1, sh1, hrow,
                                        bat, flag, Wl, gsum, N);
    // layer 2: GEMM (bf16 rows in -> quartered bf16), agg fused with pool
    k_gemm<HH, 8, unsigned short><<<(N + 7) / 8, 512, 0, stream>>>(hrow, W2, hqB, N);
    k_agg<2><<<agrid, 256, 0, stream>>>(hqB, cw, rp, dinv, sc2, sh2, nullptr,
                                        bat, flag, Wl, gsum, N);

    k_final<<<1, 256, 0, stream>>>(gsum, gcnt, bl, outp, G);
}

// Round 11
// 1169.388 us; speedup vs baseline: 1.9046x; 1.9046x over previous
//
#include <hip/hip_runtime.h>
#include <hip/hip_bf16.h>

// Problem constants (from reference)
#define NN 100000      // nodes
#define FF 128         // F_IN
#define HH 64          // HID
#define BN_EPS 1e-5f

// ---------------- dtype detection (int64 vs int32 edge/batch) ----------------
__global__ void k_detect(const unsigned* __restrict__ ei, int* __restrict__ flag) {
    if (threadIdx.x == 0 && blockIdx.x == 0) {
        unsigned o = 0;
        for (int i = 1; i < 32; i += 2) o |= ei[i];   // high words if int64
        *flag = (o == 0) ? 1 : 0;                      // 1 => int64
    }
}

__device__ __forceinline__ int load_idx(const void* p, int i, int is64) {
    return is64 ? (int)((const long long*)p)[i] : ((const int*)p)[i];
}

// ---------------- degree count ----------------
__global__ void k_count(const void* __restrict__ ei, int E, const int* __restrict__ flag,
                        int* __restrict__ counts) {
    int e = blockIdx.x * blockDim.x + threadIdx.x;
    if (e >= E) return;
    int is64 = *flag;
    int d = load_idx(ei, E + e, is64);   // dst row is second half
    atomicAdd(&counts[d], 1);
}

// ---------------- dinv + per-graph node counts ----------------
__global__ void k_dinv(const int* __restrict__ counts, float* __restrict__ dinv,
                       const void* __restrict__ bat, const int* __restrict__ flag,
                       int* __restrict__ gcnt, int N) {
    int i = blockIdx.x * blockDim.x + threadIdx.x;
    if (i >= N) return;
    float deg = (float)counts[i] + 1.0f;
    dinv[i] = rsqrtf(deg);
    int is64 = *flag;
    int b = load_idx(bat, i, is64);
    atomicAdd(&gcnt[b], 1);
}

// ---------------- 3-kernel exclusive scan (chunk = 512) ----------------
__global__ void k_scan1(const int* __restrict__ counts, int* __restrict__ partial, int N) {
    __shared__ int s[512];
    int t = threadIdx.x;
    int i = blockIdx.x * 512 + t;
    int v = (i < N) ? counts[i] : 0;
    s[t] = v; __syncthreads();
    for (int off = 256; off; off >>= 1) {
        if (t < off) s[t] += s[t + off];
        __syncthreads();
    }
    if (t == 0) partial[blockIdx.x] = s[0];
}

__global__ void k_scan2(int* __restrict__ partial, int nch) {
    __shared__ int s[256];
    int t = threadIdx.x;
    int v = (t < nch) ? partial[t] : 0;
    s[t] = v; __syncthreads();
    for (int off = 1; off < 256; off <<= 1) {
        int add = (t >= off) ? s[t - off] : 0;
        __syncthreads();
        s[t] += add;
        __syncthreads();
    }
    if (t < nch) partial[t] = s[t] - v;   // exclusive
}

__global__ void k_scan3(const int* __restrict__ counts, const int* __restrict__ partial,
                        int* __restrict__ rp, int N, int E) {
    __shared__ int s[512];
    int t = threadIdx.x;
    int i = blockIdx.x * 512 + t;
    int v = (i < N) ? counts[i] : 0;
    s[t] = v; __syncthreads();
    for (int off = 1; off < 512; off <<= 1) {
        int add = (t >= off) ? s[t - off] : 0;
        __syncthreads();
        s[t] += add;
        __syncthreads();
    }
    if (i < N) rp[i] = partial[blockIdx.x] + s[t] - v;
    if (i == N) rp[N] = E;
}

// ---------------- CSR fill: packed {src, w} ----------------
__global__ void k_fill(const void* __restrict__ ei, int E, const int* __restrict__ flag,
                       const float* __restrict__ dinv, const int* __restrict__ rp,
                       int* __restrict__ fillcnt, int2* __restrict__ cw) {
    int e = blockIdx.x * blockDim.x + threadIdx.x;
    if (e >= E) return;
    int is64 = *flag;
    int s = load_idx(ei, e, is64);
    int d = load_idx(ei, E + e, is64);
    float w = dinv[s] * dinv[d];
    int pos = rp[d] + atomicAdd(&fillcnt[d], 1);
    int2 p; p.x = s; p.y = __float_as_int(w);
    cw[pos] = p;
}

// ---------------- BN constant folding ----------------
__global__ void k_prep(const float* b1, const float* g1, const float* be1,
                       const float* m1, const float* v1,
                       const float* b2, const float* g2, const float* be2,
                       const float* m2, const float* v2,
                       float* sc1, float* sh1, float* sc2, float* sh2) {
    int f = threadIdx.x;
    if (f < HH) {
        float s1 = g1[f] * rsqrtf(v1[f] + BN_EPS);
        sc1[f] = s1; sh1[f] = (b1[f] - m1[f]) * s1 + be1[f];
        float s2 = g2[f] * rsqrtf(v2[f] + BN_EPS);
        sc2[f] = s2; sh2[f] = (b2[f] - m2[f]) * s2 + be2[f];
    }
}

// ---------------- dense GEMM: out[n][f] = sum_k x[n][k] * W[f][k] ----------------
template <int K, int NPB>
__global__ void k_gemm(const float* __restrict__ x, const float* __restrict__ W,
                       float* __restrict__ out, int N) {
    __shared__ float wT[K * (HH + 1)];
    __shared__ float xs[NPB * K];
    const int TB = NPB * 64;
    int t = threadIdx.x;
    for (int idx = t; idx < K * HH; idx += TB) {
        int f = idx / K, k = idx % K;
        wT[k * (HH + 1) + f] = W[idx];
    }
    int nb = blockIdx.x * NPB;
    for (int idx = t; idx < NPB * K; idx += TB) {
        int gi = nb * K + idx;
        xs[idx] = (gi < N * K) ? x[gi] : 0.0f;
    }
    __syncthreads();
    int f = t & 63, nl = t >> 6;
    float acc = 0.0f;
#pragma unroll
    for (int k = 0; k < K; k++)
        acc += xs[nl * K + k] * wT[k * (HH + 1) + f];
    int n = nb + nl;
    if (n < N) out[n * HH + f] = acc;
}

// ---------------- aggregation: cw-in-registers + shfl, float4 gathers ---------
// Wave per node. One coalesced 512B instruction loads 64 cw entries (one/lane);
// the edge loop gets (src,w) via UNCONDITIONAL __shfl (all 64 lanes active —
// predicated shfl reads from exec-masked lanes are undefined on CDNA, which
// was R10's silent-corruption bug). Masking is applied to the per-lane weight
// BEFORE the shfl, so padded slots pull w=0 and a duplicated (harmless) index.
template <int LAYER>
__global__ void k_agg(const float* __restrict__ h, const int2* __restrict__ cw,
                      const int* __restrict__ rp, const float* __restrict__ dinv,
                      const float* __restrict__ sc, const float* __restrict__ sh,
                      float* __restrict__ out,
                      const void* __restrict__ bat, const int* __restrict__ flag,
                      const float* __restrict__ Wl, float* __restrict__ gsum, int N) {
    int wid = (int)((blockIdx.x * blockDim.x + threadIdx.x) >> 6);
    if (wid >= N) return;
    int lane = threadIdx.x & 63;
    int q = lane >> 4;       // edge slot within 4-edge group
    int fl = lane & 15;      // float4 chunk of the 64-float row
    const float4* __restrict__ h4 = (const float4*)h;

    int s = rp[wid], e = rp[wid + 1];
    float ax = 0.f, ay = 0.f, az = 0.f, aw = 0.f;

    for (int base = s; base < e; base += 64) {
        int navail = e - base; if (navail > 64) navail = 64;
        // one coalesced 512B load: lane l holds cw[base + min(l, navail-1)]
        int li = base + (lane < navail ? lane : navail - 1);
        int2 pk = cw[li];
        int   slane = pk.x;
        float wlane = (lane < navail) ? __int_as_float(pk.y) : 0.f;  // mask BEFORE shfl
        for (int g = 0; g < navail; g += 8) {
            int i0 = g + q, i1 = g + 4 + q;          // always <= 63
            int s0 = __shfl(slane, i0);
            int s1 = __shfl(slane, i1);
            float w0 = __shfl(wlane, i0);
            float w1 = __shfl(wlane, i1);
            float4 r0 = h4[s0 * 16 + fl];
            float4 r1 = h4[s1 * 16 + fl];
            ax += w0 * r0.x + w1 * r1.x;
            ay += w0 * r0.y + w1 * r1.y;
            az += w0 * r0.z + w1 * r1.z;
            aw += w0 * r0.w + w1 * r1.w;
        }
    }
    // combine the 4 edge slots (lane bits 4,5)
    ax += __shfl_xor(ax, 16); ay += __shfl_xor(ay, 16);
    az += __shfl_xor(az, 16); aw += __shfl_xor(aw, 16);
    ax += __shfl_xor(ax, 32); ay += __shfl_xor(ay, 32);
    az += __shfl_xor(az, 32); aw += __shfl_xor(aw, 32);

    // self-loop term (added once, post-reduce)
    float di = dinv[wid];
    float di2 = di * di;
    float4 sr = h4[wid * 16 + fl];
    ax += di2 * sr.x; ay += di2 * sr.y; az += di2 * sr.z; aw += di2 * sr.w;

    // BN + ReLU on this lane's 4 features
    int f0 = fl * 4;
    float vx = fmaxf(ax * sc[f0 + 0] + sh[f0 + 0], 0.f);
    float vy = fmaxf(ay * sc[f0 + 1] + sh[f0 + 1], 0.f);
    float vz = fmaxf(az * sc[f0 + 2] + sh[f0 + 2], 0.f);
    float vw = fmaxf(aw * sc[f0 + 3] + sh[f0 + 3], 0.f);

    if (LAYER == 1) {
        if (lane < 16) {
            float4 o; o.x = vx; o.y = vy; o.z = vz; o.w = vw;
            ((float4*)out)[wid * 16 + fl] = o;
        }
    } else {
        float tval = vx * Wl[f0] + vy * Wl[f0 + 1] + vz * Wl[f0 + 2] + vw * Wl[f0 + 3];
        tval += __shfl_xor(tval, 1);
        tval += __shfl_xor(tval, 2);
        tval += __shfl_xor(tval, 4);
        tval += __shfl_xor(tval, 8);
        if (lane == 0) {
            int is64 = *flag;
            int b = load_idx(bat, wid, is64);
            atomicAdd(&gsum[b], tval);
        }
    }
}

// ---------------- final: mean + linear bias ----------------
__global__ void k_final(const float* __restrict__ gsum, const int* __restrict__ gcnt,
                        const float* __restrict__ bl, float* __restrict__ outp, int G) {
    int g = blockIdx.x * blockDim.x + threadIdx.x;
    if (g < G) outp[g] = gsum[g] / fmaxf((float)gcnt[g], 1.0f) + bl[0];
}

extern "C" void kernel_launch(void* const* d_in, const int* in_sizes, int n_in,
                              void* d_out, int out_size, void* d_ws, size_t ws_size,
                              hipStream_t stream) {
    const float* x   = (const float*)d_in[0];
    const void*  ei  = d_in[1];
    const void*  bat = d_in[2];
    const float* W1  = (const float*)d_in[3];
    const float* b1  = (const float*)d_in[4];
    const float* g1  = (const float*)d_in[5];
    const float* be1 = (const float*)d_in[6];
    const float* m1  = (const float*)d_in[7];
    const float* v1  = (const float*)d_in[8];
    const float* W2  = (const float*)d_in[9];
    const float* b2  = (const float*)d_in[10];
    const float* g2  = (const float*)d_in[11];
    const float* be2 = (const float*)d_in[12];
    const float* m2  = (const float*)d_in[13];
    const float* v2  = (const float*)d_in[14];
    const float* Wl  = (const float*)d_in[15];
    const float* bl  = (const float*)d_in[16];
    float* outp = (float*)d_out;

    const int N = NN;
    const int E = in_sizes[1] / 2;
    const int G = out_size;

    // workspace carve-up (256B aligned)
    char* base = (char*)d_ws;
    size_t off = 0;
    auto alloc = [&](size_t bytes) { void* p = base + off; off = (off + bytes + 255) & ~(size_t)255; return p; };
    int*   flag    = (int*)  alloc(16);
    float* dinv    = (float*)alloc((size_t)N * 4);
    int*   counts  = (int*)  alloc((size_t)N * 4);
    int*   rp      = (int*)  alloc(((size_t)N + 1) * 4);
    int*   fillcnt = (int*)  alloc((size_t)N * 4);
    int*   partial = (int*)  alloc(1024);
    float* sc1     = (float*)alloc(HH * 4);
    float* sh1     = (float*)alloc(HH * 4);
    float* sc2     = (float*)alloc(HH * 4);
    float* sh2     = (float*)alloc(HH * 4);
    float* gsum    = (float*)alloc((size_t)G * 4);
    int*   gcnt    = (int*)  alloc((size_t)G * 4);
    int2*  cw      = (int2*) alloc((size_t)E * 8);
    float* bufA    = (float*)alloc((size_t)N * HH * 4);   // h1, later h2
    float* bufB    = (float*)alloc((size_t)N * HH * 4);   // h2in
    (void)ws_size;

    // zero accumulators (fresh every call)
    hipMemsetAsync(counts, 0, (size_t)N * 4, stream);
    hipMemsetAsync(fillcnt, 0, (size_t)N * 4, stream);
    hipMemsetAsync(gsum, 0, (size_t)G * 4, stream);
    hipMemsetAsync(gcnt, 0, (size_t)G * 4, stream);

    k_detect<<<1, 64, 0, stream>>>((const unsigned*)ei, flag);

    int eb = (E + 255) / 256;
    k_count<<<eb, 256, 0, stream>>>(ei, E, flag, counts);

    int nb = (N + 255) / 256;
    k_dinv<<<nb, 256, 0, stream>>>(counts, dinv, bat, flag, gcnt, N);

    int nch = (N + 511) / 512;
    k_scan1<<<nch, 512, 0, stream>>>(counts, partial, N);
    k_scan2<<<1, 256, 0, stream>>>(partial, nch);
    k_scan3<<<nch, 512, 0, stream>>>(counts, partial, rp, N, E);

    k_fill<<<eb, 256, 0, stream>>>(ei, E, flag, dinv, rp, fillcnt, cw);

    k_prep<<<1, 64, 0, stream>>>(b1, g1, be1, m1, v1, b2, g2, be2, m2, v2,
                                 sc1, sh1, sc2, sh2);

    // layer 1
    k_gemm<FF, 8><<<(N + 7) / 8, 512, 0, stream>>>(x, W1, bufA, N);
    k_agg<1><<<(N + 3) / 4, 256, 0, stream>>>(bufA, cw, rp, dinv, sc1, sh1, bufB,
                                              bat, flag, Wl, gsum, N);
    // layer 2
    k_gemm<HH, 8><<<(N + 7) / 8, 512, 0, stream>>>(bufB, W2, bufA, N);
    k_agg<2><<<(N + 3) / 4, 256, 0, stream>>>(bufA, cw, rp, dinv, sc2, sh2, nullptr,
                                              bat, flag, Wl, gsum, N);

    k_final<<<1, 256, 0, stream>>>(gsum, gcnt, bl, outp, G);
}